// Round 5
// baseline (373.812 us; speedup 1.0000x reference)
//
#include <hip/hip_runtime.h>
#include <stdint.h>

#define NROWS 32768
#define KP    4000
#define KPAD  4096
#define DIM   128
#define CL    1000
#define HREAL 125          // 125 halves x 32 proxies = 4000 exactly

typedef unsigned short u16;
typedef unsigned long long u64;
typedef unsigned short u16x8 __attribute__((ext_vector_type(8)));
typedef __bf16 bf16x8 __attribute__((ext_vector_type(8)));
typedef float f32x16 __attribute__((ext_vector_type(16)));
typedef float f32x4 __attribute__((ext_vector_type(4)));   // for nontemporal stores

// ---------- helpers ----------

// Map float to a 32-bit key with the same total order (handles negatives).
__device__ __forceinline__ unsigned int f2ord(float f) {
    unsigned int u = __float_as_uint(f);
    return (u & 0x80000000u) ? ~u : (u | 0x80000000u);
}

__device__ __forceinline__ u16 bf16rne(float f) {
    unsigned u = __float_as_uint(f);
    return (u16)((u + 0x7FFFu + ((u >> 16) & 1u)) >> 16);
}
__device__ __forceinline__ float bf2f(u16 h) {
    return __uint_as_float(((unsigned)h) << 16);
}
// 3-way bf16 split: v ~= h + m + l with |err| ~ 2^-27 |v|
__device__ __forceinline__ void split3(float v, u16& h, u16& m, u16& l) {
    h = bf16rne(v);
    float r1 = v - bf2f(h);
    m = bf16rne(r1);
    float r2 = r1 - bf2f(m);
    l = bf16rne(r2);
}

__device__ __forceinline__ f32x16 mfma16(bf16x8 a, bf16x8 b, f32x16 c) {
    return __builtin_amdgcn_mfma_f32_32x32x16_bf16(a, b, c, 0, 0, 0);
}

// async global->LDS 16B per lane; dest must be linear (base + lane*16).
__device__ __forceinline__ void g2lds16(const void* g, void* l) {
    __builtin_amdgcn_global_load_lds(
        (const __attribute__((address_space(1))) unsigned int*)(uintptr_t)g,
        (__attribute__((address_space(3))) unsigned int*)(uintptr_t)l,
        16, 0, 0);
}

// nontemporal 16B store wrapper (clang builtin needs ext-vector, not float4)
__device__ __forceinline__ void nt_store4(const float4& v, float4* dst) {
    __builtin_nontemporal_store(*(const f32x4*)&v, (f32x4*)dst);
}

// ---------- prep ----------
// psplit_sw layout (ushort): [half:128][s:3][row:32][chunkpos:16][e:8]
//   chunkpos = chunk ^ (row & 7)  -- pre-swizzled so argmin stages with
//   linear global_load_lds (rule #21).
// xfrag layout (ushort): [g:1024][kk:8][s:3][lane:64][e:8]
//   element (g,kk,s,lane,e) = x_s[g*32 + (lane&31)][kk*16 + (lane>>5)*8 + e]
__global__ void prep_kernel(const float* __restrict__ x,
                            const float* __restrict__ proxies,
                            u16* __restrict__ xfrag,
                            u16* __restrict__ psplit_sw,
                            float* __restrict__ p2pad,
                            u64* __restrict__ packed) {
    int i = blockIdx.x * 256 + threadIdx.x;        // grid 1408*256 = 360448
    if (i < NROWS) packed[i] = ~0ull;
    if (i < KPAD) {
        if (i < KP) {
            const float4* p = (const float4*)(proxies + (size_t)i * DIM);
            float s = 0.f;
            #pragma unroll
            for (int d = 0; d < DIM / 4; d++) {
                float4 v = p[d];
                s = fmaf(v.x, v.x, s);
                s = fmaf(v.y, v.y, s);
                s = fmaf(v.z, v.z, s);
                s = fmaf(v.w, v.w, s);
            }
            p2pad[i] = s;
        } else {
            p2pad[i] = __builtin_inff();           // padded proxies never win
        }
    }
    if (i >= 32768 && i < 98304) {                 // proxy splits: (k, 8-col chunk)
        int j = i - 32768;
        int k = j >> 4, c = j & 15;
        float vals[8];
        if (k < KP) {
            const float4* p = (const float4*)(proxies + (size_t)k * DIM + c * 8);
            float4 a = p[0], b = p[1];
            vals[0]=a.x; vals[1]=a.y; vals[2]=a.z; vals[3]=a.w;
            vals[4]=b.x; vals[5]=b.y; vals[6]=b.z; vals[7]=b.w;
        } else {
            #pragma unroll
            for (int e = 0; e < 8; e++) vals[e] = 0.f;
        }
        u16x8 vh, vm, vl;
        #pragma unroll
        for (int e = 0; e < 8; e++) {
            u16 h, m, l; split3(vals[e], h, m, l);
            vh[e] = h; vm[e] = m; vl[e] = l;
        }
        u16* dst = psplit_sw + (size_t)(k >> 5) * 12288 +
                   (size_t)(k & 31) * 128 + ((c ^ (k & 7)) << 3);
        *(u16x8*)(dst)        = vh;
        *(u16x8*)(dst + 4096) = vm;                // s stride = 32*128
        *(u16x8*)(dst + 8192) = vl;
    }
    if (i >= 98304) {                              // x fragments: (n, kk)
        int j = i - 98304;                         // [0, 262144)
        int n = j & 32767, kk = j >> 15;
        const float4* xp = (const float4*)(x + (size_t)n * DIM + kk * 16);
        float4 a = xp[0], b = xp[1], cc = xp[2], d4 = xp[3];
        float vals[16] = {a.x,a.y,a.z,a.w, b.x,b.y,b.z,b.w,
                          cc.x,cc.y,cc.z,cc.w, d4.x,d4.y,d4.z,d4.w};
        u16x8 h0,h1,m0,m1,l0v,l1v;
        #pragma unroll
        for (int e = 0; e < 8; e++) {
            u16 h,m,l; split3(vals[e], h,m,l);
            h0[e]=h; m0[e]=m; l0v[e]=l;
        }
        #pragma unroll
        for (int e = 0; e < 8; e++) {
            u16 h,m,l; split3(vals[8+e], h,m,l);
            h1[e]=h; m1[e]=m; l1v[e]=l;
        }
        int g = n >> 5, ln = n & 31;
        u16* base = xfrag + (size_t)g*12288 + (size_t)kk*1536 + (size_t)ln*8;
        *(u16x8*)(base)        = h0;               // lane ln   (d = kk*16+0..7)
        *(u16x8*)(base + 512)  = m0;
        *(u16x8*)(base + 1024) = l0v;
        u16* base1 = base + 256;                   // lane ln+32 (d = kk*16+8..15)
        *(u16x8*)(base1)        = h1;
        *(u16x8*)(base1 + 512)  = m1;
        *(u16x8*)(base1 + 1024) = l1v;
    }
}

// ---------- argmin: 64 x-rows/wave, 4 MFMA chains, pipelined epilogue ----------
// 256 thr = 4 waves; wave w owns rows [blockIdx.x*256 + w*64, +64) as TWO
// B-register sets (row-set 0/1). Proxies stream through double-buffered
// 2x24KB LDS half-tiles (32 proxies x 3 splits) via linear global_load_lds
// from the pre-swizzled image. Each A-fragment read feeds 4 MFMAs.
// Score eval of half h-1 is interleaved into half h's MFMA clusters
// (register-only; fills pipe-stall issue slots). p2 prefetched 1 half ahead.
// grid = (128, 2): 2 k-columns, 63/62 halves. 1 block/CU, 1 wave/SIMD.
__global__ void __launch_bounds__(256, 1)
argmin_mfma(const u16* __restrict__ xfrag,
            const u16* __restrict__ psplit_sw,
            const float* __restrict__ p2pad,
            u64* __restrict__ packed) {
    __shared__ __align__(16) u16 buf[2][12288];    // 2 x 24KB
    const int tid  = threadIdx.x;
    const int lane = tid & 63;
    const int w    = tid >> 6;
    const int r31  = lane & 31;
    const int hl   = lane >> 5;
    const int r7   = r31 & 7;
    const int g0   = blockIdx.x * 8 + w * 2;       // row-set 0 group; +1 = set 1

    // B fragments: x splits for 64 rows (2 sets x 3 splits x 8 kk) = 192 VGPRs
    bf16x8 xf0[3][8], xf1[3][8];
    {
        const u16* b0 = xfrag + (size_t)g0 * 12288 + lane * 8;
        #pragma unroll
        for (int kk = 0; kk < 8; kk++)
            #pragma unroll
            for (int s = 0; s < 3; s++) {
                xf0[s][kk] = *(const bf16x8*)(b0 + (kk*3 + s) * 512);
                xf1[s][kk] = *(const bf16x8*)(b0 + 12288 + (kk*3 + s) * 512);
            }
    }

    const int h0 = (blockIdx.y == 0) ? 0  : 63;
    const int h1 = (blockIdx.y == 0) ? 63 : HREAL;

    const int soff = w * 3072 + lane * 8;          // linear stage slice (u16)

    // prologue: stage h0
    {
        const u16* src = psplit_sw + (size_t)h0 * 12288 + soff;
        u16* dst = &buf[h0 & 1][0] + soff;
        #pragma unroll
        for (int j = 0; j < 6; j++) g2lds16(src + j*512, dst + j*512);
    }
    __syncthreads();

    float best0 = __builtin_inff(), best1 = __builtin_inff();
    int bk0 = 0, bk1 = 0;
    f32x16 sA = {0}, sB = {0}, sC = {0}, sD = {0}; // prev-half accs (pipelined)
    float4 qp[4] = {};                             // prev-half p2 quads
    int skb = -1;                                  // prev-half k base

    for (int h = h0; h < h1; ++h) {
        const int p = h & 1;
        // issue next half's stage first (flies under the MFMAs)
        if (h + 1 < h1) {
            const u16* src = psplit_sw + (size_t)(h + 1) * 12288 + soff;
            u16* dst = &buf[p ^ 1][0] + soff;
            #pragma unroll
            for (int j = 0; j < 6; j++) g2lds16(src + j*512, dst + j*512);
        }
        // prefetch p2 for CURRENT half (consumed next iteration)
        float4 qc[4];
        {
            const float* q = p2pad + (h << 5) + (hl << 2);
            #pragma unroll
            for (int j = 0; j < 4; j++) qc[j] = *(const float4*)(q + (j << 3));
        }

        const u16* B = &buf[p][0];
        f32x16 acc0 = {0,0,0,0,0,0,0,0,0,0,0,0,0,0,0,0};  // rs0, even kk
        f32x16 acc1 = {0,0,0,0,0,0,0,0,0,0,0,0,0,0,0,0};  // rs0, odd kk
        f32x16 acc2 = {0,0,0,0,0,0,0,0,0,0,0,0,0,0,0,0};  // rs1, even kk
        f32x16 acc3 = {0,0,0,0,0,0,0,0,0,0,0,0,0,0,0,0};  // rs1, odd kk
        __builtin_amdgcn_s_setprio(1);
        #pragma unroll
        for (int i = 0; i < 4; i++) {
            const int kk = i * 2;
            int c0 = ((kk << 1) | hl) ^ r7;        // swizzled 16B chunk index
            int c1 = (((kk + 1) << 1) | hl) ^ r7;
            const u16* b0 = B + (r31 << 7) + (c0 << 3);
            const u16* b1 = B + (r31 << 7) + (c1 << 3);
            bf16x8 a0h = *(const bf16x8*)(b0);
            bf16x8 a0m = *(const bf16x8*)(b0 + 4096);
            bf16x8 a0l = *(const bf16x8*)(b0 + 8192);
            bf16x8 a1h = *(const bf16x8*)(b1);
            bf16x8 a1m = *(const bf16x8*)(b1 + 4096);
            bf16x8 a1l = *(const bf16x8*)(b1 + 8192);
            // 6 terms (hh,hm,mh,hl,lh,mm) x 2 row-sets x 2 K-halves = 24 MFMA
            acc0 = mfma16(a0h, xf0[0][kk],   acc0);
            acc1 = mfma16(a1h, xf0[0][kk+1], acc1);
            acc2 = mfma16(a0h, xf1[0][kk],   acc2);
            acc3 = mfma16(a1h, xf1[0][kk+1], acc3);
            acc0 = mfma16(a0h, xf0[1][kk],   acc0);
            acc1 = mfma16(a1h, xf0[1][kk+1], acc1);
            acc2 = mfma16(a0h, xf1[1][kk],   acc2);
            acc3 = mfma16(a1h, xf1[1][kk+1], acc3);
            acc0 = mfma16(a0m, xf0[0][kk],   acc0);
            acc1 = mfma16(a1m, xf0[0][kk+1], acc1);
            acc2 = mfma16(a0m, xf1[0][kk],   acc2);
            acc3 = mfma16(a1m, xf1[0][kk+1], acc3);
            acc0 = mfma16(a0h, xf0[2][kk],   acc0);
            acc1 = mfma16(a1h, xf0[2][kk+1], acc1);
            acc2 = mfma16(a0h, xf1[2][kk],   acc2);
            acc3 = mfma16(a1h, xf1[2][kk+1], acc3);
            acc0 = mfma16(a0l, xf0[0][kk],   acc0);
            acc1 = mfma16(a1l, xf0[0][kk+1], acc1);
            acc2 = mfma16(a0l, xf1[0][kk],   acc2);
            acc3 = mfma16(a1l, xf1[0][kk+1], acc3);
            acc0 = mfma16(a0m, xf0[1][kk],   acc0);
            acc1 = mfma16(a1m, xf0[1][kk+1], acc1);
            acc2 = mfma16(a0m, xf1[1][kk],   acc2);
            acc3 = mfma16(a1m, xf1[1][kk+1], acc3);
            // pipelined epilogue: score chunk i of PREVIOUS half (reg-only)
            if (skb >= 0) {
                float4 qv = qp[i];
                float qa[4] = {qv.x, qv.y, qv.z, qv.w};
                #pragma unroll
                for (int e = 0; e < 4; e++) {
                    int ki = skb + (hl << 2) + (i << 3) + e;
                    float d0 = sA[i*4 + e] + sB[i*4 + e];
                    float s0 = fmaf(-2.f, d0, qa[e]);
                    if (s0 < best0) { best0 = s0; bk0 = ki; }  // strict <
                    float d1 = sC[i*4 + e] + sD[i*4 + e];
                    float s1 = fmaf(-2.f, d1, qa[e]);
                    if (s1 < best1) { best1 = s1; bk1 = ki; }
                }
            }
        }
        __builtin_amdgcn_s_setprio(0);

        asm volatile("s_waitcnt vmcnt(0)" ::: "memory");   // next half staged
        __syncthreads();

        sA = acc0; sB = acc1; sC = acc2; sD = acc3;        // rotate pipeline
        #pragma unroll
        for (int j = 0; j < 4; j++) qp[j] = qc[j];
        skb = h << 5;
    }

    // drain: score the last half
    #pragma unroll
    for (int i = 0; i < 4; i++) {
        float4 qv = qp[i];
        float qa[4] = {qv.x, qv.y, qv.z, qv.w};
        #pragma unroll
        for (int e = 0; e < 4; e++) {
            int ki = skb + (hl << 2) + (i << 3) + e;
            float d0 = sA[i*4 + e] + sB[i*4 + e];
            float s0 = fmaf(-2.f, d0, qa[e]);
            if (s0 < best0) { best0 = s0; bk0 = ki; }
            float d1 = sC[i*4 + e] + sD[i*4 + e];
            float s1 = fmaf(-2.f, d1, qa[e]);
            if (s1 < best1) { best1 = s1; bk1 = ki; }
        }
    }

    u64 key0 = ((u64)f2ord(best0) << 32) | (unsigned)bk0;
    u64 key1 = ((u64)f2ord(best1) << 32) | (unsigned)bk1;
    u64 o0 = __shfl_xor(key0, 32); key0 = o0 < key0 ? o0 : key0;
    u64 o1 = __shfl_xor(key1, 32); key1 = o1 < key1 ? o1 : key1;
    if (hl == 0) {
        size_t row0 = (size_t)g0 * 32 + r31;       // row-set 0
        atomicMin(&packed[row0], key0);
        atomicMin(&packed[row0 + 32], key1);       // row-set 1
    }
}

// ---------- epilogue copies ----------

// out[N*D : 2*N*D) = proxies[idx]
__global__ void copy_proxy(const float4* __restrict__ prox4,
                           const u64* __restrict__ packed,
                           float4* __restrict__ out4) {
    int i = blockIdx.x * 256 + threadIdx.x;          // 4096 x 256 = N*32
    int n = i >> 5;                                  // DIM/4 = 32
    int d = i & 31;
    int k = (int)(unsigned int)(packed[n] & 0xFFFFFFFFull);
    nt_store4(prox4[(size_t)k * 32 + d], out4 + i);
}

// out[2*N*D : ...) = labels[idx] ; 4 rows/block, 1 wave per row
__global__ void gather_labels(const float4* __restrict__ lab4,
                              const u64* __restrict__ packed,
                              float4* __restrict__ out4) {
    int rr = threadIdx.x >> 6;
    int ln = threadIdx.x & 63;
    int n = blockIdx.x * 4 + rr;                     // 8192 blocks
    int k = (int)(unsigned int)(packed[n] & 0xFFFFFFFFull);
    const float4* src = lab4 + (size_t)k * (CL / 4);
    float4* dst = out4 + (size_t)n * (CL / 4);
    for (int d = ln; d < CL / 4; d += 64)
        nt_store4(src[d], dst + d);
}

extern "C" void kernel_launch(void* const* d_in, const int* in_sizes, int n_in,
                              void* d_out, int out_size, void* d_ws, size_t ws_size,
                              hipStream_t stream) {
    const float* x       = (const float*)d_in[0];
    const float* proxies = (const float*)d_in[1];
    const float* labels  = (const float*)d_in[2];
    float* out = (float*)d_out;

    // workspace map (~28MB):
    //   [0, 256K)        packed u64[32768]
    //   [256K, 272K)     p2pad f32[4096]
    //   [512K, 3.5M)     psplit_sw u16 [128][3][32][128] (pre-swizzled)
    //   [4M, 28M)        xfrag u16 [1024][8][3][64][8]
    u64*   packed    = (u64*)d_ws;
    float* p2pad     = (float*)((char*)d_ws + 262144);
    u16*   psplit_sw = (u16*)((char*)d_ws + 524288);
    u16*   xfrag     = (u16*)((char*)d_ws + 4194304);

    prep_kernel<<<1408, 256, 0, stream>>>(x, proxies, xfrag, psplit_sw,
                                          p2pad, packed);

    argmin_mfma<<<dim3(128, 2), 256, 0, stream>>>(xfrag, psplit_sw, p2pad, packed);

    // out[0 : N*D) = x  (pure D2D copy; graph-capture-legal)
    hipMemcpyAsync(out, x, (size_t)NROWS * DIM * sizeof(float),
                   hipMemcpyDeviceToDevice, stream);

    copy_proxy<<<4096, 256, 0, stream>>>(
        (const float4*)proxies, packed, (float4*)(out + (size_t)NROWS * DIM));

    gather_labels<<<8192, 256, 0, stream>>>(
        (const float4*)labels, packed, (float4*)(out + 2L * NROWS * DIM));
}